// Round 1
// baseline (363.134 us; speedup 1.0000x reference)
//
#include <hip/hip_runtime.h>
#include <hip/hip_bf16.h>

#define NROWS 256
#define INF 768
#define NSHORT 2000
#define NHEAD 2003

typedef __attribute__((ext_vector_type(8))) short s16x8;
typedef __attribute__((ext_vector_type(4))) float f32x4;

__device__ __forceinline__ float sigf(float z) { return 1.f / (1.f + __expf(-z)); }
__device__ __forceinline__ float softplusf(float z) {
    return fmaxf(z, 0.f) + __logf(1.f + __expf(-fabsf(z)));
}
__device__ __forceinline__ float qreduce16(float v) {
    v += __shfl_xor(v, 1); v += __shfl_xor(v, 2);
    v += __shfl_xor(v, 4); v += __shfl_xor(v, 8);
    return v;
}
__device__ __forceinline__ float wreduce64(float v) {
    v += __shfl_xor(v, 1);  v += __shfl_xor(v, 2);  v += __shfl_xor(v, 4);
    v += __shfl_xor(v, 8);  v += __shfl_xor(v, 16); v += __shfl_xor(v, 32);
    return v;
}

// Generic bf16-MFMA GEMM core: C[256,N] = A[256,K](bf16) * W[N,K](f32, bf16-converted).
// Block = 256 thr = 4 waves; wave w owns rows [64w,64w+64), block owns cols [64*nb, 64*nb+64).
// MODE 0: store f32. MODE 1: store f32 + rowacc += softplus(z) for col<NSHORT.
// MODE 2: rowacc += sum_j -max(log1p(-r*sig(z)), -100), r = sigmoid(rootlogit[row*3]).
template <int MODE>
__device__ __forceinline__ void gemm_core(
    const __hip_bfloat16* __restrict__ A, const float* __restrict__ W,
    int N, int K, int nb,
    float* __restrict__ outZ, int ldZ,
    float* __restrict__ rowacc, const float* __restrict__ rootlogit)
{
    __shared__ __align__(16) __hip_bfloat16 Wb[64][40];  // pad 32->40: 2-way bank alias (free)
    const int t = threadIdx.x;
    const int wave = t >> 6, lane = t & 63;
    const int quad = lane >> 4, l16 = lane & 15;
    const int col0 = nb * 64, row0 = wave * 64;

    f32x4 acc[4][4];
    const f32x4 zf = {0.f, 0.f, 0.f, 0.f};
#pragma unroll
    for (int i = 0; i < 4; i++)
#pragma unroll
        for (int j = 0; j < 4; j++) acc[i][j] = zf;

    const int wrow = t >> 2;             // 0..63: W row within tile
    const int koff = (t & 3) * 8;        // 0,8,16,24
    const bool wok = (col0 + wrow) < N;
    const float* wsrc = W + (size_t)(col0 + wrow) * K + koff;

    for (int kk = 0; kk < K; kk += 32) {
        float4 va = {0.f, 0.f, 0.f, 0.f}, vb = {0.f, 0.f, 0.f, 0.f};
        if (wok) {
            va = *(const float4*)(wsrc + kk);
            vb = *(const float4*)(wsrc + kk + 4);
        }
        __syncthreads();  // previous chunk's readers done
        __hip_bfloat16 tmp[8];
        tmp[0] = __float2bfloat16(va.x); tmp[1] = __float2bfloat16(va.y);
        tmp[2] = __float2bfloat16(va.z); tmp[3] = __float2bfloat16(va.w);
        tmp[4] = __float2bfloat16(vb.x); tmp[5] = __float2bfloat16(vb.y);
        tmp[6] = __float2bfloat16(vb.z); tmp[7] = __float2bfloat16(vb.w);
        *(s16x8*)(&Wb[wrow][koff]) = *(const s16x8*)tmp;
        __syncthreads();  // writes visible

        s16x8 bfrag[4], afrag[4];
#pragma unroll
        for (int ct = 0; ct < 4; ct++)
            bfrag[ct] = *(const s16x8*)(&Wb[ct * 16 + l16][quad * 8]);
#pragma unroll
        for (int rt = 0; rt < 4; rt++)
            afrag[rt] = *(const s16x8*)(A + (size_t)(row0 + rt * 16 + l16) * K + kk + quad * 8);
#pragma unroll
        for (int rt = 0; rt < 4; rt++)
#pragma unroll
            for (int ct = 0; ct < 4; ct++)
                acc[rt][ct] = __builtin_amdgcn_mfma_f32_16x16x32_bf16(
                    afrag[rt], bfrag[ct], acc[rt][ct], 0, 0, 0);
    }

    if (MODE != 2) {
#pragma unroll
        for (int rt = 0; rt < 4; rt++) {
#pragma unroll
            for (int r = 0; r < 4; r++) {
                const int row = row0 + rt * 16 + quad * 4 + r;  // C/D: row=quad*4+reg
                float sum = 0.f;
#pragma unroll
                for (int ct = 0; ct < 4; ct++) {
                    const int col = col0 + ct * 16 + l16;       // C/D: col=lane&15
                    const float z = acc[rt][ct][r];
                    if (col < N) {
                        outZ[(size_t)row * ldZ + col] = z;
                        if (MODE == 1 && col < NSHORT) sum += softplusf(z);
                    }
                }
                if (MODE == 1) {
                    sum = qreduce16(sum);
                    if (l16 == 0) atomicAdd(&rowacc[row], sum);
                }
            }
        }
    } else {
#pragma unroll
        for (int rt = 0; rt < 4; rt++) {
#pragma unroll
            for (int r = 0; r < 4; r++) {
                const int row = row0 + rt * 16 + quad * 4 + r;
                const float rv = sigf(rootlogit[row * 3]);
                float sum = 0.f;
#pragma unroll
                for (int ct = 0; ct < 4; ct++) {
                    const int col = col0 + ct * 16 + l16;
                    if (col < N) {
                        const float p = rv * sigf(acc[rt][ct][r]);
                        sum += -fmaxf(__logf(1.f - p), -100.f);
                    }
                }
                sum = qreduce16(sum);
                if (l16 == 0) atomicAdd(&rowacc[row], sum);
            }
        }
    }
}

__global__ __launch_bounds__(256) void k_cvt(const float* __restrict__ x,
                                             __hip_bfloat16* __restrict__ xb) {
    const int i = blockIdx.x * 256 + threadIdx.x;  // grid covers exactly 256*768
    xb[i] = __float2bfloat16(x[i]);
}

// Exact fp32 root logits: head_W rows 2000..2002 (used coherently across ~60k terms/row)
__global__ __launch_bounds__(64) void k_roots(const float* __restrict__ x,
                                              const float* __restrict__ headW,
                                              float* __restrict__ rootlogit) {
    const int b = blockIdx.x, lane = threadIdx.x;
    const float* xr = x + b * INF;
    for (int i = 0; i < 3; i++) {
        const float* wr = headW + (size_t)(NSHORT + i) * INF;
        float s = 0.f;
        for (int k = lane; k < INF; k += 64) s += xr[k] * wr[k];
        s = wreduce64(s);
        if (lane == 0) rootlogit[b * 3 + i] = s;
    }
}

__global__ __launch_bounds__(256) void k_head(const __hip_bfloat16* __restrict__ xb,
                                              const float* __restrict__ headW,
                                              float* __restrict__ logits,
                                              float* __restrict__ headacc) {
    gemm_core<1>(xb, headW, NHEAD, INF, blockIdx.x, logits, NHEAD, headacc, nullptr);
}

__global__ __launch_bounds__(256) void k_w1(const __hip_bfloat16* __restrict__ xb,
                                            const float* w10, const float* w11, const float* w12,
                                            float* h0, float* h1, float* h2) {
    const int bx = blockIdx.x;  // 6 + 3 + 2 = 11 blocks
    if (bx < 6)      gemm_core<0>(xb, w10, 384, INF, bx,     h0, 384, nullptr, nullptr);
    else if (bx < 9) gemm_core<0>(xb, w11, 192, INF, bx - 6, h1, 192, nullptr, nullptr);
    else             gemm_core<0>(xb, w12,  96, INF, bx - 9, h2,  96, nullptr, nullptr);
}

__global__ __launch_bounds__(64) void k_ln(const float* h0, const float* h1, const float* h2,
                                           const float* g0, const float* g1, const float* g2,
                                           const float* b0, const float* b1, const float* b2,
                                           __hip_bfloat16* o0, __hip_bfloat16* o1,
                                           __hip_bfloat16* o2) {
    const int bx = blockIdx.x, ci = bx >> 8, row = bx & 255, lane = threadIdx.x;
    const float *h, *g, *bb; __hip_bfloat16* o; int hsz;
    if (ci == 0)      { h = h0; g = g0; bb = b0; o = o0; hsz = 384; }
    else if (ci == 1) { h = h1; g = g1; bb = b1; o = o1; hsz = 192; }
    else              { h = h2; g = g2; bb = b2; o = o2; hsz = 96;  }
    const float* hr = h + row * hsz;
    float s = 0.f, s2 = 0.f;
    for (int k = lane; k < hsz; k += 64) { const float v = hr[k]; s += v; s2 += v * v; }
    s = wreduce64(s); s2 = wreduce64(s2);
    const float mu = s / hsz;
    const float var = s2 / hsz - mu * mu;
    const float rs = rsqrtf(var + 1e-5f);
    for (int k = lane; k < hsz; k += 64) {
        const float v = (hr[k] - mu) * rs * g[k] + bb[k];
        o[row * hsz + k] = __float2bfloat16(fmaxf(v, 0.f));
    }
}

__global__ __launch_bounds__(256) void k_bce(const __hip_bfloat16* hb0,
                                             const __hip_bfloat16* hb1,
                                             const __hip_bfloat16* hb2,
                                             const float* w20, const float* w21, const float* w22,
                                             float* clusteracc, const float* rootlogit) {
    const int bx = blockIdx.x;  // 157 + 438 + 938 = 1533 blocks
    if (bx < 157)
        gemm_core<2>(hb0, w20, 10000, 384, bx,       nullptr, 0, clusteracc,       rootlogit + 0);
    else if (bx < 595)
        gemm_core<2>(hb1, w21, 28000, 192, bx - 157, nullptr, 0, clusteracc + 256, rootlogit + 1);
    else
        gemm_core<2>(hb2, w22, 60000,  96, bx - 595, nullptr, 0, clusteracc + 512, rootlogit + 2);
}

// One wave per (row, target-slot): dedupe, then target-position corrections.
__global__ __launch_bounds__(64) void k_corr(const int* __restrict__ target,
                                             const float* __restrict__ logits,
                                             const float* __restrict__ rootlogit,
                                             const __hip_bfloat16* hb0,
                                             const __hip_bfloat16* hb1,
                                             const __hip_bfloat16* hb2,
                                             const float* w20, const float* w21, const float* w22,
                                             float* headacc, float* clusteracc) {
    const int b = blockIdx.x / 20, l = blockIdx.x % 20, lane = threadIdx.x;
    const int t = target[b * 20 + l];
    for (int m = 0; m < l; m++)
        if (target[b * 20 + m] == t) return;  // multi-hot: duplicates count once
    if (t < NSHORT) {
        if (lane == 0) atomicAdd(&headacc[b], -logits[(size_t)b * NHEAD + t]);  // y=1: -z
        return;
    }
    int ci, low, hsz; const __hip_bfloat16* hb; const float* w2;
    if (t < 12000)      { ci = 0; low = 2000;  hsz = 384; hb = hb0; w2 = w20; }
    else if (t < 40000) { ci = 1; low = 12000; hsz = 192; hb = hb1; w2 = w21; }
    else                { ci = 2; low = 40000; hsz = 96;  hb = hb2; w2 = w22; }
    const __hip_bfloat16* hr = hb + b * hsz;
    const float* wr = w2 + (size_t)(t - low) * hsz;
    float z = 0.f;
    for (int k = lane; k < hsz; k += 64) z += __bfloat162float(hr[k]) * wr[k];
    z = wreduce64(z);
    if (lane == 0) {
        const float rv = sigf(rootlogit[b * 3 + ci]);
        const float p = rv * sigf(z);
        const float corr = -fmaxf(__logf(p), -100.f) + fmaxf(__logf(1.f - p), -100.f);
        atomicAdd(&clusteracc[ci * 256 + b], corr);
    }
}

__global__ __launch_bounds__(256) void k_final(const int* __restrict__ target,
                                               const float* __restrict__ rootlogit,
                                               const float* __restrict__ headacc,
                                               const float* __restrict__ clusteracc,
                                               float* __restrict__ out) {
    const int b = threadIdx.x;
    bool act[3] = {false, false, false};
    for (int l = 0; l < 20; l++) {
        const int t = target[b * 20 + l];
        if (t >= 2000) {
            if (t < 12000) act[0] = true;
            else if (t < 40000) act[1] = true;
            else act[2] = true;
        }
    }
    float hs = headacc[b];
    float total = 0.f;
    float num = 2000.f;
    const float csz[3] = {10000.f, 28000.f, 60000.f};
    for (int i = 0; i < 3; i++) {
        const float zi = rootlogit[b * 3 + i];
        if (act[i]) { total += clusteracc[i * 256 + b]; num += csz[i]; }
        else        { hs += softplusf(zi); num += 1.f; }  // mult=1, y=0
    }
    const float val = (hs + total) / num;
    __shared__ float red[256];
    red[b] = val;
    __syncthreads();
    for (int s = 128; s > 0; s >>= 1) {
        if (b < s) red[b] += red[b + s];
        __syncthreads();
    }
    if (b == 0) out[0] = red[0] / 256.f;
}

extern "C" void kernel_launch(void* const* d_in, const int* in_sizes, int n_in,
                              void* d_out, int out_size, void* d_ws, size_t ws_size,
                              hipStream_t stream) {
    const float* x      = (const float*)d_in[0];
    const float* headW  = (const float*)d_in[1];
    const int*   target = (const int*)d_in[2];
    const float* w10 = (const float*)d_in[3];
    const float* g0  = (const float*)d_in[4];
    const float* b0  = (const float*)d_in[5];
    const float* w20 = (const float*)d_in[6];
    const float* w11 = (const float*)d_in[7];
    const float* g1  = (const float*)d_in[8];
    const float* b1  = (const float*)d_in[9];
    const float* w21 = (const float*)d_in[10];
    const float* w12 = (const float*)d_in[11];
    const float* g2  = (const float*)d_in[12];
    const float* b2  = (const float*)d_in[13];
    const float* w22 = (const float*)d_in[14];
    float* out = (float*)d_out;

    char* ws = (char*)d_ws;
    size_t off = 0;
    auto carve = [&](size_t bytes) -> void* {
        void* p = ws + off;
        off += (bytes + 255) & ~(size_t)255;
        return p;
    };
    __hip_bfloat16* xb  = (__hip_bfloat16*)carve((size_t)256 * 768 * 2);
    float* logits       = (float*)carve((size_t)256 * NHEAD * 4);
    float* h0           = (float*)carve((size_t)256 * 384 * 4);
    float* h1           = (float*)carve((size_t)256 * 192 * 4);
    float* h2           = (float*)carve((size_t)256 * 96 * 4);
    __hip_bfloat16* hb0 = (__hip_bfloat16*)carve((size_t)256 * 384 * 2);
    __hip_bfloat16* hb1 = (__hip_bfloat16*)carve((size_t)256 * 192 * 2);
    __hip_bfloat16* hb2 = (__hip_bfloat16*)carve((size_t)256 * 96 * 2);
    float* rootlogit    = (float*)carve((size_t)256 * 3 * 4);
    float* headacc      = (float*)carve((size_t)256 * 4);      // 1024 B (256-aligned)
    float* clusteracc   = (float*)carve((size_t)3 * 256 * 4);  // contiguous after headacc

    hipMemsetAsync(headacc, 0, 4096, stream);  // headacc + clusteracc

    k_cvt<<<768, 256, 0, stream>>>(x, xb);
    k_roots<<<256, 64, 0, stream>>>(x, headW, rootlogit);
    k_head<<<32, 256, 0, stream>>>(xb, headW, logits, headacc);
    k_w1<<<11, 256, 0, stream>>>(xb, w10, w11, w12, h0, h1, h2);
    k_ln<<<768, 64, 0, stream>>>(h0, h1, h2, g0, g1, g2, b0, b1, b2, hb0, hb1, hb2);
    k_bce<<<1533, 256, 0, stream>>>(hb0, hb1, hb2, w20, w21, w22, clusteracc, rootlogit);
    k_corr<<<5120, 64, 0, stream>>>(target, logits, rootlogit, hb0, hb1, hb2,
                                    w20, w21, w22, headacc, clusteracc);
    k_final<<<1, 256, 0, stream>>>(target, rootlogit, headacc, clusteracc, out);

    (void)in_sizes; (void)n_in; (void)out_size; (void)ws_size;
}

// Round 2
// 274.639 us; speedup vs baseline: 1.3222x; 1.3222x over previous
//
#include <hip/hip_runtime.h>
#include <hip/hip_bf16.h>

#define NROWS 256
#define INF 768
#define NSHORT 2000
#define NHEAD 2003
#define NBCE 1533          // 157 + 438 + 938 bce blocks
#define PSTRIDE 1536       // padded partial stride per row

typedef __attribute__((ext_vector_type(8))) short s16x8;
typedef __attribute__((ext_vector_type(4))) float f32x4;

__device__ __forceinline__ float sigf(float z) { return 1.f / (1.f + __expf(-z)); }
__device__ __forceinline__ float softplusf(float z) {
    return fmaxf(z, 0.f) + __logf(1.f + __expf(-fabsf(z)));
}
__device__ __forceinline__ float qreduce16(float v) {
    v += __shfl_xor(v, 1); v += __shfl_xor(v, 2);
    v += __shfl_xor(v, 4); v += __shfl_xor(v, 8);
    return v;
}
__device__ __forceinline__ float wreduce64(float v) {
    v += __shfl_xor(v, 1);  v += __shfl_xor(v, 2);  v += __shfl_xor(v, 4);
    v += __shfl_xor(v, 8);  v += __shfl_xor(v, 16); v += __shfl_xor(v, 32);
    return v;
}

// bf16-MFMA GEMM core: C[256,N] = A[256,K](bf16) * W[N,K](f32 -> bf16).
// Block = 4 waves; wave w owns rows [64w,64w+64); block owns cols [64nb, 64nb+64).
// MODE 0: store z (f32).
// MODE 1: store z + part[row] = sum_{col<NSHORT} softplus(z)          (plain store)
// MODE 2: part[row*PSTRIDE] = sum_col -max(log1p(-r*sig(z)),-100)     (plain store)
template <int MODE>
__device__ __forceinline__ void gemm_core(
    const __hip_bfloat16* __restrict__ A, const float* __restrict__ W,
    int N, int K, int nb,
    float* __restrict__ outZ, int ldZ,
    float* __restrict__ part, const float* __restrict__ rootlogit)
{
    __shared__ __align__(16) __hip_bfloat16 Wb[64][40];  // pad: worst 2-way alias (free)
    const int t = threadIdx.x;
    const int wave = t >> 6, lane = t & 63;
    const int quad = lane >> 4, l16 = lane & 15;
    const int col0 = nb * 64, row0 = wave * 64;

    f32x4 acc[4][4];
    const f32x4 zf = {0.f, 0.f, 0.f, 0.f};
#pragma unroll
    for (int i = 0; i < 4; i++)
#pragma unroll
        for (int j = 0; j < 4; j++) acc[i][j] = zf;

    const int wrow = t >> 2;             // 0..63: W row within tile
    const int koff = (t & 3) * 8;        // 0,8,16,24
    const bool wok = (col0 + wrow) < N;
    const float* wsrc = W + (size_t)(col0 + wrow) * K + koff;

    float4 va = {0.f, 0.f, 0.f, 0.f}, vb = {0.f, 0.f, 0.f, 0.f};
    if (wok) { va = *(const float4*)(wsrc); vb = *(const float4*)(wsrc + 4); }

    for (int kk = 0; kk < K; kk += 32) {
        __hip_bfloat16 tmp[8];
        tmp[0] = __float2bfloat16(va.x); tmp[1] = __float2bfloat16(va.y);
        tmp[2] = __float2bfloat16(va.z); tmp[3] = __float2bfloat16(va.w);
        tmp[4] = __float2bfloat16(vb.x); tmp[5] = __float2bfloat16(vb.y);
        tmp[6] = __float2bfloat16(vb.z); tmp[7] = __float2bfloat16(vb.w);
        __syncthreads();  // previous chunk's readers done
        *(s16x8*)(&Wb[wrow][koff]) = *(const s16x8*)tmp;
        __syncthreads();  // writes visible

        if (kk + 32 < K && wok) {  // prefetch next W chunk: overlaps ds_read+MFMA below
            va = *(const float4*)(wsrc + kk + 32);
            vb = *(const float4*)(wsrc + kk + 36);
        }

        s16x8 bfrag[4], afrag[4];
#pragma unroll
        for (int ct = 0; ct < 4; ct++)
            bfrag[ct] = *(const s16x8*)(&Wb[ct * 16 + l16][quad * 8]);
#pragma unroll
        for (int rt = 0; rt < 4; rt++)
            afrag[rt] = *(const s16x8*)(A + (size_t)(row0 + rt * 16 + l16) * K + kk + quad * 8);
#pragma unroll
        for (int rt = 0; rt < 4; rt++)
#pragma unroll
            for (int ct = 0; ct < 4; ct++)
                acc[rt][ct] = __builtin_amdgcn_mfma_f32_16x16x32_bf16(
                    afrag[rt], bfrag[ct], acc[rt][ct], 0, 0, 0);
    }

    if (MODE != 2) {
#pragma unroll
        for (int rt = 0; rt < 4; rt++) {
#pragma unroll
            for (int r = 0; r < 4; r++) {
                const int row = row0 + rt * 16 + quad * 4 + r;  // C/D: row=quad*4+reg
                float sum = 0.f;
#pragma unroll
                for (int ct = 0; ct < 4; ct++) {
                    const int col = col0 + ct * 16 + l16;       // C/D: col=lane&15
                    const float z = acc[rt][ct][r];
                    if (col < N) {
                        outZ[(size_t)row * ldZ + col] = z;
                        if (MODE == 1 && col < NSHORT) sum += softplusf(z);
                    }
                }
                if (MODE == 1) {
                    sum = qreduce16(sum);
                    if (l16 == 0) part[row] = sum;   // private slice: plain store
                }
            }
        }
    } else {
#pragma unroll
        for (int rt = 0; rt < 4; rt++) {
#pragma unroll
            for (int r = 0; r < 4; r++) {
                const int row = row0 + rt * 16 + quad * 4 + r;
                const float rv = sigf(rootlogit[row * 3]);
                float sum = 0.f;
#pragma unroll
                for (int ct = 0; ct < 4; ct++) {
                    const int col = col0 + ct * 16 + l16;
                    if (col < N) {
                        const float p = rv * sigf(acc[rt][ct][r]);
                        sum += -fmaxf(__logf(1.f - p), -100.f);
                    }
                }
                sum = qreduce16(sum);
                if (l16 == 0) part[(size_t)row * PSTRIDE] = sum;  // private column: plain store
            }
        }
    }
}

__global__ __launch_bounds__(256) void k_cvt(const float* __restrict__ x,
                                             __hip_bfloat16* __restrict__ xb) {
    const int i = blockIdx.x * 256 + threadIdx.x;
    xb[i] = __float2bfloat16(x[i]);
}

// Exact fp32 root logits (used coherently across ~60k terms/row -> keep fp32)
__global__ __launch_bounds__(64) void k_roots(const float* __restrict__ x,
                                              const float* __restrict__ headW,
                                              float* __restrict__ rootlogit) {
    const int b = blockIdx.x, lane = threadIdx.x;
    const float* xr = x + b * INF;
    for (int i = 0; i < 3; i++) {
        const float* wr = headW + (size_t)(NSHORT + i) * INF;
        float s = 0.f;
        for (int k = lane; k < INF; k += 64) s += xr[k] * wr[k];
        s = wreduce64(s);
        if (lane == 0) rootlogit[b * 3 + i] = s;
    }
}

__global__ __launch_bounds__(256) void k_head(const __hip_bfloat16* __restrict__ xb,
                                              const float* __restrict__ headW,
                                              float* __restrict__ logits,
                                              float* __restrict__ phead) {
    gemm_core<1>(xb, headW, NHEAD, INF, blockIdx.x, logits, NHEAD,
                 phead + blockIdx.x * 256, nullptr);
}

__global__ __launch_bounds__(256) void k_w1(const __hip_bfloat16* __restrict__ xb,
                                            const float* w10, const float* w11, const float* w12,
                                            float* h0, float* h1, float* h2) {
    const int bx = blockIdx.x;  // 6 + 3 + 2 = 11 blocks
    if (bx < 6)      gemm_core<0>(xb, w10, 384, INF, bx,     h0, 384, nullptr, nullptr);
    else if (bx < 9) gemm_core<0>(xb, w11, 192, INF, bx - 6, h1, 192, nullptr, nullptr);
    else             gemm_core<0>(xb, w12,  96, INF, bx - 9, h2,  96, nullptr, nullptr);
}

__global__ __launch_bounds__(64) void k_ln(const float* h0, const float* h1, const float* h2,
                                           const float* g0, const float* g1, const float* g2,
                                           const float* b0, const float* b1, const float* b2,
                                           __hip_bfloat16* o0, __hip_bfloat16* o1,
                                           __hip_bfloat16* o2) {
    const int bx = blockIdx.x, ci = bx >> 8, row = bx & 255, lane = threadIdx.x;
    const float *h, *g, *bb; __hip_bfloat16* o; int hsz;
    if (ci == 0)      { h = h0; g = g0; bb = b0; o = o0; hsz = 384; }
    else if (ci == 1) { h = h1; g = g1; bb = b1; o = o1; hsz = 192; }
    else              { h = h2; g = g2; bb = b2; o = o2; hsz = 96;  }
    const float* hr = h + row * hsz;
    float s = 0.f, s2 = 0.f;
    for (int k = lane; k < hsz; k += 64) { const float v = hr[k]; s += v; s2 += v * v; }
    s = wreduce64(s); s2 = wreduce64(s2);
    const float mu = s / hsz;
    const float var = s2 / hsz - mu * mu;
    const float rs = rsqrtf(var + 1e-5f);
    for (int k = lane; k < hsz; k += 64) {
        const float v = (hr[k] - mu) * rs * g[k] + bb[k];
        o[row * hsz + k] = __float2bfloat16(fmaxf(v, 0.f));
    }
}

__global__ __launch_bounds__(256) void k_bce(const __hip_bfloat16* hb0,
                                             const __hip_bfloat16* hb1,
                                             const __hip_bfloat16* hb2,
                                             const float* w20, const float* w21, const float* w22,
                                             float* pbce, const float* rootlogit) {
    const int bx = blockIdx.x;  // 157 + 438 + 938 = 1533 blocks
    if (bx < 157)
        gemm_core<2>(hb0, w20, 10000, 384, bx,       nullptr, 0, pbce + bx, rootlogit + 0);
    else if (bx < 595)
        gemm_core<2>(hb1, w21, 28000, 192, bx - 157, nullptr, 0, pbce + bx, rootlogit + 1);
    else
        gemm_core<2>(hb2, w22, 60000,  96, bx - 595, nullptr, 0, pbce + bx, rootlogit + 2);
}

// Reduce pbce[row][0..NBCE) into per-cluster per-row sums. One block per row.
__global__ __launch_bounds__(256) void k_red(const float* __restrict__ pbce,
                                             float* __restrict__ clusteracc) {
    const int row = blockIdx.x, t = threadIdx.x;
    const float* pr = pbce + (size_t)row * PSTRIDE;
    float c0 = 0.f, c1 = 0.f, c2 = 0.f;
    for (int i = t; i < NBCE; i += 256) {
        const float v = pr[i];
        if (i < 157) c0 += v; else if (i < 595) c1 += v; else c2 += v;
    }
    c0 = wreduce64(c0); c1 = wreduce64(c1); c2 = wreduce64(c2);
    __shared__ float red[3][4];
    const int wave = t >> 6, lane = t & 63;
    if (lane == 0) { red[0][wave] = c0; red[1][wave] = c1; red[2][wave] = c2; }
    __syncthreads();
    if (t < 3) {
        clusteracc[t * 256 + row] = red[t][0] + red[t][1] + red[t][2] + red[t][3];
    }
}

// One wave per (row, target-slot): dedupe, then per-target corrections.
__global__ __launch_bounds__(64) void k_corr(const int* __restrict__ target,
                                             const float* __restrict__ logits,
                                             const float* __restrict__ rootlogit,
                                             const __hip_bfloat16* hb0,
                                             const __hip_bfloat16* hb1,
                                             const __hip_bfloat16* hb2,
                                             const float* w20, const float* w21, const float* w22,
                                             float* headcorr, float* clusteracc) {
    const int b = blockIdx.x / 20, l = blockIdx.x % 20, lane = threadIdx.x;
    const int t = target[b * 20 + l];
    for (int m = 0; m < l; m++)
        if (target[b * 20 + m] == t) return;  // multi-hot: duplicates count once
    if (t < NSHORT) {
        if (lane == 0) atomicAdd(&headcorr[b], -logits[(size_t)b * NHEAD + t]);  // y=1: -z
        return;
    }
    int ci, low, hsz; const __hip_bfloat16* hb; const float* w2;
    if (t < 12000)      { ci = 0; low = 2000;  hsz = 384; hb = hb0; w2 = w20; }
    else if (t < 40000) { ci = 1; low = 12000; hsz = 192; hb = hb1; w2 = w21; }
    else                { ci = 2; low = 40000; hsz = 96;  hb = hb2; w2 = w22; }
    const __hip_bfloat16* hr = hb + b * hsz;
    const float* wr = w2 + (size_t)(t - low) * hsz;
    float z = 0.f;
    for (int k = lane; k < hsz; k += 64) z += __bfloat162float(hr[k]) * wr[k];
    z = wreduce64(z);
    if (lane == 0) {
        const float rv = sigf(rootlogit[b * 3 + ci]);
        const float p = rv * sigf(z);
        const float corr = -fmaxf(__logf(p), -100.f) + fmaxf(__logf(1.f - p), -100.f);
        atomicAdd(&clusteracc[ci * 256 + b], corr);  // runs after k_red
    }
}

__global__ __launch_bounds__(256) void k_final(const int* __restrict__ target,
                                               const float* __restrict__ rootlogit,
                                               const float* __restrict__ phead,
                                               const float* __restrict__ headcorr,
                                               const float* __restrict__ clusteracc,
                                               float* __restrict__ out) {
    const int b = threadIdx.x;
    bool act[3] = {false, false, false};
    for (int l = 0; l < 20; l++) {
        const int t = target[b * 20 + l];
        if (t >= 2000) {
            if (t < 12000) act[0] = true;
            else if (t < 40000) act[1] = true;
            else act[2] = true;
        }
    }
    float hs = headcorr[b];
    for (int i = 0; i < 32; i++) hs += phead[i * 256 + b];  // head partials (32 blocks)
    float total = 0.f;
    float num = 2000.f;
    const float csz[3] = {10000.f, 28000.f, 60000.f};
    for (int i = 0; i < 3; i++) {
        const float zi = rootlogit[b * 3 + i];
        if (act[i]) { total += clusteracc[i * 256 + b]; num += csz[i]; }
        else        { hs += softplusf(zi); num += 1.f; }  // mult=1, y=0
    }
    const float val = (hs + total) / num;
    __shared__ float red[256];
    red[b] = val;
    __syncthreads();
    for (int s = 128; s > 0; s >>= 1) {
        if (b < s) red[b] += red[b + s];
        __syncthreads();
    }
    if (b == 0) out[0] = red[0] / 256.f;
}

extern "C" void kernel_launch(void* const* d_in, const int* in_sizes, int n_in,
                              void* d_out, int out_size, void* d_ws, size_t ws_size,
                              hipStream_t stream) {
    const float* x      = (const float*)d_in[0];
    const float* headW  = (const float*)d_in[1];
    const int*   target = (const int*)d_in[2];
    const float* w10 = (const float*)d_in[3];
    const float* g0  = (const float*)d_in[4];
    const float* b0  = (const float*)d_in[5];
    const float* w20 = (const float*)d_in[6];
    const float* w11 = (const float*)d_in[7];
    const float* g1  = (const float*)d_in[8];
    const float* b1  = (const float*)d_in[9];
    const float* w21 = (const float*)d_in[10];
    const float* w12 = (const float*)d_in[11];
    const float* g2  = (const float*)d_in[12];
    const float* b2  = (const float*)d_in[13];
    const float* w22 = (const float*)d_in[14];
    float* out = (float*)d_out;

    char* ws = (char*)d_ws;
    size_t off = 0;
    auto carve = [&](size_t bytes) -> void* {
        void* p = ws + off;
        off += (bytes + 255) & ~(size_t)255;
        return p;
    };
    __hip_bfloat16* xb  = (__hip_bfloat16*)carve((size_t)256 * 768 * 2);
    float* logits       = (float*)carve((size_t)256 * NHEAD * 4);
    float* h0           = (float*)carve((size_t)256 * 384 * 4);
    float* h1           = (float*)carve((size_t)256 * 192 * 4);
    float* h2           = (float*)carve((size_t)256 * 96 * 4);
    __hip_bfloat16* hb0 = (__hip_bfloat16*)carve((size_t)256 * 384 * 2);
    __hip_bfloat16* hb1 = (__hip_bfloat16*)carve((size_t)256 * 192 * 2);
    __hip_bfloat16* hb2 = (__hip_bfloat16*)carve((size_t)256 * 96 * 2);
    float* rootlogit    = (float*)carve((size_t)256 * 3 * 4);
    float* phead        = (float*)carve((size_t)32 * 256 * 4);
    float* pbce         = (float*)carve((size_t)256 * PSTRIDE * 4);  // [row][bce block]
    float* headcorr     = (float*)carve((size_t)256 * 4);
    float* clusteracc   = (float*)carve((size_t)3 * 256 * 4);

    hipMemsetAsync(headcorr, 0, 1024, stream);  // only the correction accumulator

    k_cvt<<<768, 256, 0, stream>>>(x, xb);
    k_roots<<<256, 64, 0, stream>>>(x, headW, rootlogit);
    k_head<<<32, 256, 0, stream>>>(xb, headW, logits, phead);
    k_w1<<<11, 256, 0, stream>>>(xb, w10, w11, w12, h0, h1, h2);
    k_ln<<<768, 64, 0, stream>>>(h0, h1, h2, g0, g1, g2, b0, b1, b2, hb0, hb1, hb2);
    k_bce<<<NBCE, 256, 0, stream>>>(hb0, hb1, hb2, w20, w21, w22, pbce, rootlogit);
    k_red<<<256, 256, 0, stream>>>(pbce, clusteracc);
    k_corr<<<5120, 64, 0, stream>>>(target, logits, rootlogit, hb0, hb1, hb2,
                                    w20, w21, w22, headcorr, clusteracc);
    k_final<<<1, 256, 0, stream>>>(target, rootlogit, phead, headcorr, clusteracc, out);

    (void)in_sizes; (void)n_in; (void)out_size; (void)ws_size;
}